// Round 10
// baseline (597.051 us; speedup 1.0000x reference)
//
#include <hip/hip_runtime.h>
#include <hip/hip_bf16.h>
#include <hip/hip_fp16.h>

#define NN 100000
#define EE 500000
#define NP 100096  // NN padded to 1564*64

typedef _Float16 f16;
typedef __attribute__((ext_vector_type(8))) _Float16 f16x8;
typedef __attribute__((ext_vector_type(4))) _Float16 f16x4;
typedef __attribute__((ext_vector_type(4))) float f32x4;

static __device__ __forceinline__ f16x8 relu8(f16x8 a) {
#if __has_builtin(__builtin_elementwise_max)
  f16x8 z = {0, 0, 0, 0, 0, 0, 0, 0};
  return __builtin_elementwise_max(a, z);
#else
  f16x8 r;
#pragma unroll
  for (int i = 0; i < 8; ++i) r[i] = (a[i] > (f16)0) ? a[i] : (f16)0;
  return r;
#endif
}

// ---------------- init: W1/W2 -> MFMA-fragment order, zero deg, zero stat slices (merged)
__global__ __launch_bounds__(256) void init_kernel(const float* __restrict__ W1,
                                                   const float* __restrict__ W2,
                                                   f16* __restrict__ w1f,
                                                   f16* __restrict__ w2f,
                                                   int* __restrict__ deg,
                                                   float* __restrict__ slices) {
  int gid = blockIdx.x * 256 + threadIdx.x;
  if (gid < 163840) {
    int l = gid / 32768; int rem = gid % 32768;
    int k = rem / 256;   int n = rem % 256;
    int ctg = n >> 4, m = n & 15;
    int c = k >> 5, q = (k >> 3) & 3, e = k & 7;
    int lane = q * 16 + m;
    w1f[l * 32768 + ((ctg * 4 + c) * 64 + lane) * 8 + e] = (f16)W1[gid];
  } else if (gid < 327680) {
    int g = gid - 163840;
    int l = g / 32768; int rem = g % 32768;
    int k = rem / 128; int n = rem % 128;
    int ctg = n >> 4, m = n & 15;
    int c = k >> 5, q = (k >> 3) & 3, e = k & 7;
    int lane = q * 16 + m;
    w2f[l * 32768 + ((ctg * 8 + c) * 64 + lane) * 8 + e] = (f16)W2[g];
  } else if (gid < 427680) {
    int i = gid - 327680;
    if (i < NN) deg[i] = 0;
  } else if (gid < 439968) {
    slices[gid - 427680] = 0.f;
  }
}

// ---------------- bond-sum table: tab[l][combo][d] = sum_f bemb[l][f][a_f][d], combo=a0|a1<<3|a2<<6
__global__ __launch_bounds__(256) void bondtab_kernel(const float* __restrict__ bemb,
                                                      f16* __restrict__ tab) {
  int gid = blockIdx.x * 256 + threadIdx.x; // 1280 blocks = 327,680 = 5*512*128
  int l = gid >> 16;
  int rem = gid & 65535;
  int combo = rem >> 7, d = rem & 127;
  int a0 = combo & 7, a1 = (combo >> 3) & 7, a2 = combo >> 6;
  const float* bl = bemb + l * 3072;
  float v = bl[a0 * 128 + d] + bl[1024 + a1 * 128 + d] + bl[2048 + a2 * 128 + d];
  tab[gid] = (f16)v;
}

// ---------------- CSR build ----------------
__global__ __launch_bounds__(256) void hist_kernel(const int* __restrict__ ei, int* __restrict__ deg) {
  int e = blockIdx.x * 256 + threadIdx.x;
  if (e < EE) atomicAdd(&deg[ei[EE + e]], 1);
}

__global__ __launch_bounds__(256) void scan1_kernel(const int* __restrict__ deg,
                                                    int* __restrict__ offs,
                                                    int* __restrict__ bsum) {
  __shared__ int sh[256];
  int b = blockIdx.x, t = threadIdx.x;
  int base = b * 1024 + t * 4;
  int v[4];
  int s = 0;
#pragma unroll
  for (int i = 0; i < 4; ++i) { v[i] = (base + i < NN) ? deg[base + i] : 0; s += v[i]; }
  sh[t] = s;
  __syncthreads();
  for (int off = 1; off < 256; off <<= 1) {
    int x = (t >= off) ? sh[t - off] : 0;
    __syncthreads();
    sh[t] += x;
    __syncthreads();
  }
  int excl = sh[t] - s;
  if (t == 255) bsum[b] = sh[255];
  int run = excl;
#pragma unroll
  for (int i = 0; i < 4; ++i) {
    if (base + i < NN) offs[base + i] = run;
    run += v[i];
  }
}

__global__ void scan2_kernel(int* __restrict__ bsum, int nb) {
  if (threadIdx.x == 0 && blockIdx.x == 0) {
    int run = 0;
    for (int i = 0; i < nb; ++i) { int v = bsum[i]; bsum[i] = run; run += v; }
  }
}

__global__ __launch_bounds__(256) void scan3_kernel(int* __restrict__ offs,
                                                    const int* __restrict__ bsum,
                                                    int* __restrict__ cursor) {
  int i = blockIdx.x * 256 + threadIdx.x;
  if (i < NN) {
    int v = offs[i] + bsum[i >> 10];
    offs[i] = v;
    cursor[i] = v;
  } else if (i == NN) {
    offs[NN] = EE;
  }
}

// pkw.x = src(17b) | a0<<17 | a1<<20 | a2<<23 ; pkw.y = bits of edge weight
__global__ __launch_bounds__(256) void scatter_kernel(const int* __restrict__ ei,
                                                      const int* __restrict__ ea,
                                                      const float* __restrict__ ew,
                                                      int* __restrict__ cursor,
                                                      int2* __restrict__ pkw) {
  int e = blockIdx.x * 256 + threadIdx.x;
  if (e >= EE) return;
  int dst = ei[EE + e];
  int pos = atomicAdd(&cursor[dst], 1);
  int src = ei[e];
  int a0 = ea[e * 3 + 0], a1 = ea[e * 3 + 1], a2 = ea[e * 3 + 2];
  pkw[pos] = make_int2(src | (a0 << 17) | (a1 << 20) | (a2 << 23), __float_as_int(ew[e]));
}

// ---------------- atom embedding: hf16[n,d] = (f16) sum_f atom_emb[f, x[n,f], d] ----------------
__global__ __launch_bounds__(256) void atom_kernel(const int* __restrict__ x,
                                                   const float* __restrict__ aemb,
                                                   f16* __restrict__ hf) {
  int gid = blockIdx.x * 256 + threadIdx.x;
  int n = gid >> 5, qq = gid & 31;
  if (n >= NN) return;
  float4 s = {0.f, 0.f, 0.f, 0.f};
#pragma unroll
  for (int f = 0; f < 9; ++f) {
    int xi = x[n * 9 + f];
    float4 v = *(const float4*)(aemb + (f * 120 + xi) * 128 + qq * 4);
    s.x += v.x; s.y += v.y; s.z += v.z; s.w += v.w;
  }
  f16x4 o;
  o[0] = (f16)s.x; o[1] = (f16)s.y; o[2] = (f16)s.z; o[3] = (f16)s.w;
  *(f16x4*)(hf + (long)n * 128 + qq * 4) = o;
}

// ---------------- edge aggregate, layer 0: z = (1+eps)*h + sum relu(h[src]+bsum)*w
// 2-deep software pipeline; packed pkw (one 8B load per edge-thread).
__global__ __launch_bounds__(256) void edge_agg_kernel(const int* __restrict__ offs,
                                                       const int2* __restrict__ pkw,
                                                       const f16* __restrict__ tab, // l=0 slice
                                                       const float* __restrict__ eps,
                                                       const f16* __restrict__ hf,
                                                       f16* __restrict__ zb) {
  int gid = blockIdx.x * 256 + threadIdx.x; // NP*16 threads exactly
  int n = gid >> 4, d0 = (gid & 15) * 8;
  if (n >= NN) {
    f16x8 z = {0, 0, 0, 0, 0, 0, 0, 0};
    *(f16x8*)(zb + (long)n * 128 + d0) = z;
    return;
  }
  int s0 = offs[n], s1 = offs[n + 1];
  float e1 = 1.f + eps[0];
  f16x8 hn = *(const f16x8*)(hf + (long)n * 128 + d0);
  float acc[8];
#pragma unroll
  for (int i = 0; i < 8; ++i) acc[i] = e1 * (float)hn[i];

  float wA, wB; f16x8 hA, bA, hB, bB;
  if (s0 < s1) {
    int2 pw = pkw[s0]; wA = __int_as_float(pw.y);
    hA = *(const f16x8*)(hf + (long)(pw.x & 131071) * 128 + d0);
    bA = *(const f16x8*)(tab + ((pw.x >> 17) & 511) * 128 + d0);
  }
  if (s0 + 1 < s1) {
    int2 pw = pkw[s0 + 1]; wB = __int_as_float(pw.y);
    hB = *(const f16x8*)(hf + (long)(pw.x & 131071) * 128 + d0);
    bB = *(const f16x8*)(tab + ((pw.x >> 17) & 511) * 128 + d0);
  }
  int e = s0;
  for (; e + 1 < s1; e += 2) {
    {
      f16x8 sm = relu8(hA + bA);
#pragma unroll
      for (int i = 0; i < 8; ++i) acc[i] += (float)sm[i] * wA;
      if (e + 2 < s1) {
        int2 pw = pkw[e + 2]; wA = __int_as_float(pw.y);
        hA = *(const f16x8*)(hf + (long)(pw.x & 131071) * 128 + d0);
        bA = *(const f16x8*)(tab + ((pw.x >> 17) & 511) * 128 + d0);
      }
    }
    {
      f16x8 sm = relu8(hB + bB);
#pragma unroll
      for (int i = 0; i < 8; ++i) acc[i] += (float)sm[i] * wB;
      if (e + 3 < s1) {
        int2 pw = pkw[e + 3]; wB = __int_as_float(pw.y);
        hB = *(const f16x8*)(hf + (long)(pw.x & 131071) * 128 + d0);
        bB = *(const f16x8*)(tab + ((pw.x >> 17) & 511) * 128 + d0);
      }
    }
  }
  if (e < s1) {
    f16x8 sm = relu8(hA + bA);
#pragma unroll
    for (int i = 0; i < 8; ++i) acc[i] += (float)sm[i] * wA;
  }
  f16x8 o;
#pragma unroll
  for (int i = 0; i < 8; ++i) o[i] = (f16)acc[i];
  *(f16x8*)(zb + (long)n * 128 + d0) = o;
}

// ---------------- edge aggregate, layers 1..4: h = relu(BN2(t2)) on the fly (packed f16),
// 2-deep pipeline, packed pkw; block 0 re-zeroes sum1s/sq1s for this layer's gemm1.
__global__ __launch_bounds__(256) void edge_agg_bn_kernel(const int* __restrict__ offs,
                                                          const int2* __restrict__ pkw,
                                                          const f16* __restrict__ tab, // + l*65536
                                                          const float* __restrict__ eps, int l,
                                                          const f16* __restrict__ t2,  // prev t2 (hf buf)
                                                          const float* __restrict__ sum2s,
                                                          const float* __restrict__ sq2s,
                                                          const float* __restrict__ g2,  // g_out+(l-1)*128
                                                          const float* __restrict__ bt2, // bt_out+(l-1)*128
                                                          float* __restrict__ s1z,       // sum1s base (8192 f32)
                                                          f16* __restrict__ zb) {
  __shared__ float sc2[128], sh2[128];
  const int tid = threadIdx.x;
  if (tid < 128) {
    float s = 0.f, s2 = 0.f;
#pragma unroll
    for (int k = 0; k < 16; ++k) { s += sum2s[k * 128 + tid]; s2 += sq2s[k * 128 + tid]; }
    float mu = s * (1.f / NN);
    float var = fmaxf(s2 * (1.f / NN) - mu * mu, 0.f);
    float is = rsqrtf(var + 1e-5f);
    float sc = g2[tid] * is;
    sc2[tid] = sc;
    sh2[tid] = bt2[tid] - mu * sc;
  }
  if (blockIdx.x == 0) { // re-zero sum1s+sq1s for this layer's gemm1
#pragma unroll
    for (int j = 0; j < 8; ++j)
      *(float4*)(s1z + (j * 256 + tid) * 4) = float4{0.f, 0.f, 0.f, 0.f};
  }
  __syncthreads();
  int gid = blockIdx.x * 256 + tid;
  int n = gid >> 4, d0 = (gid & 15) * 8;
  if (n >= NN) {
    f16x8 z = {0, 0, 0, 0, 0, 0, 0, 0};
    *(f16x8*)(zb + (long)n * 128 + d0) = z;
    return;
  }
  float4 svA = *(const float4*)(sc2 + d0), svB = *(const float4*)(sc2 + d0 + 4);
  float4 shA = *(const float4*)(sh2 + d0), shB = *(const float4*)(sh2 + d0 + 4);
  float sv[8] = {svA.x, svA.y, svA.z, svA.w, svB.x, svB.y, svB.z, svB.w};
  float hv[8] = {shA.x, shA.y, shA.z, shA.w, shB.x, shB.y, shB.z, shB.w};
  f16x8 sv8, hv8;
#pragma unroll
  for (int i = 0; i < 8; ++i) { sv8[i] = (f16)sv[i]; hv8[i] = (f16)hv[i]; }

  int s0 = offs[n], s1 = offs[n + 1];
  float e1 = 1.f + eps[l];
  f16x8 hn = *(const f16x8*)(t2 + (long)n * 128 + d0);
  float acc[8];
#pragma unroll
  for (int i = 0; i < 8; ++i)
    acc[i] = e1 * fmaxf((float)hn[i] * sv[i] + hv[i], 0.f);

  float wA, wB; f16x8 hA, bA, hB, bB;
  if (s0 < s1) {
    int2 pw = pkw[s0]; wA = __int_as_float(pw.y);
    hA = *(const f16x8*)(t2 + (long)(pw.x & 131071) * 128 + d0);
    bA = *(const f16x8*)(tab + ((pw.x >> 17) & 511) * 128 + d0);
  }
  if (s0 + 1 < s1) {
    int2 pw = pkw[s0 + 1]; wB = __int_as_float(pw.y);
    hB = *(const f16x8*)(t2 + (long)(pw.x & 131071) * 128 + d0);
    bB = *(const f16x8*)(tab + ((pw.x >> 17) & 511) * 128 + d0);
  }
  int e = s0;
  for (; e + 1 < s1; e += 2) {
    {
      f16x8 y = relu8(hA * sv8 + hv8);
      f16x8 sm = relu8(y + bA);
#pragma unroll
      for (int i = 0; i < 8; ++i) acc[i] += (float)sm[i] * wA;
      if (e + 2 < s1) {
        int2 pw = pkw[e + 2]; wA = __int_as_float(pw.y);
        hA = *(const f16x8*)(t2 + (long)(pw.x & 131071) * 128 + d0);
        bA = *(const f16x8*)(tab + ((pw.x >> 17) & 511) * 128 + d0);
      }
    }
    {
      f16x8 y = relu8(hB * sv8 + hv8);
      f16x8 sm = relu8(y + bB);
#pragma unroll
      for (int i = 0; i < 8; ++i) acc[i] += (float)sm[i] * wB;
      if (e + 3 < s1) {
        int2 pw = pkw[e + 3]; wB = __int_as_float(pw.y);
        hB = *(const f16x8*)(t2 + (long)(pw.x & 131071) * 128 + d0);
        bB = *(const f16x8*)(tab + ((pw.x >> 17) & 511) * 128 + d0);
      }
    }
  }
  if (e < s1) {
    f16x8 y = relu8(hA * sv8 + hv8);
    f16x8 sm = relu8(y + bA);
#pragma unroll
    for (int i = 0; i < 8; ++i) acc[i] += (float)sm[i] * wA;
  }
  f16x8 o;
#pragma unroll
  for (int i = 0; i < 8; ++i) o[i] = (f16)acc[i];
  *(f16x8*)(zb + (long)n * 128 + d0) = o;
}

// ---------------- GEMM1: t1 = z @ W1, grid 1564 — each block does BOTH 128-col halves
// (A staged+fragment-loaded ONCE: halves gemm1's A fetch vs the (2,1564) grid).
// Block 0 re-zeroes sum2s/sq2s for this layer's gemm2 atomics.
__global__ __launch_bounds__(256) void gemm1_kernel(const f16* __restrict__ zb,
                                                    const f16* __restrict__ w1f, // +l*32768, frag order
                                                    f16* __restrict__ t1f,
                                                    float* __restrict__ sum1s,
                                                    float* __restrict__ sq1s,
                                                    float* __restrict__ s2z) { // sum2s base (4096 f32)
  __shared__ __align__(16) char ldsraw[17408]; // A-stage 16KB; epilogue [64][136] f16
  const int tid = threadIdx.x;
  const int lane = tid & 63, w = tid >> 6;
  const int wr = w >> 1, wc = w & 1;
  const int m = lane & 15, q = lane >> 4;
  const int rbase = blockIdx.x * 64;
  const int slice = blockIdx.x & 15;

  if (blockIdx.x == 0) { // re-zero sum2s+sq2s
#pragma unroll
    for (int j = 0; j < 4; ++j)
      *(float4*)(s2z + (j * 256 + tid) * 4) = float4{0.f, 0.f, 0.f, 0.f};
  }

  // ---- stage A tile (64 x 128 f16 = 16KB): 4 x 16B per thread, contiguous global
  {
    f16x8 st[4];
    const int tofs = tid * 16;
#pragma unroll
    for (int j = 0; j < 4; ++j)
      st[j] = *(const f16x8*)(zb + (long)rbase * 128 + (tofs + j * 4096) / 2);
#pragma unroll
    for (int j = 0; j < 4; ++j) {
      int ofs = tofs + j * 4096;
      int row = ofs >> 8, colb = ofs & 255;
      *(f16x8*)(ldsraw + row * 256 + (colb ^ ((row & 7) << 4))) = st[j];
    }
  }
  __syncthreads();

  // ---- A fragments from LDS (swizzled, conflict-free), held across both halves
  f16x8 A[2][4];
#pragma unroll
  for (int rt = 0; rt < 2; ++rt) {
    int row = wr * 32 + rt * 16 + m;
    int rs = row * 256, sw = (row & 7) << 4;
#pragma unroll
    for (int c = 0; c < 4; ++c) {
      int colb = c * 64 + q * 16;
      A[rt][c] = *(const f16x8*)(ldsraw + rs + (colb ^ sw));
    }
  }
  __syncthreads(); // all waves past A-stage reads; LDS reusable as epilogue buffer

  f16 (*sh)[136] = (f16(*)[136])ldsraw;
  const int colc = tid & 15, r0 = tid >> 4;

#pragma unroll
  for (int h = 0; h < 2; ++h) {
    // B fragments for this half: lane-contiguous 1KB loads, L1/L2-hot
    f16x8 B[4][4];
#pragma unroll
    for (int ct = 0; ct < 4; ++ct)
#pragma unroll
      for (int c = 0; c < 4; ++c)
        B[ct][c] = *(const f16x8*)(w1f + (((h * 8 + wc * 4 + ct) * 4 + c) * 64 + lane) * 8);

    f32x4 acc[2][4];
    const f32x4 zf = {0.f, 0.f, 0.f, 0.f};
#pragma unroll
    for (int a = 0; a < 2; ++a)
#pragma unroll
      for (int b = 0; b < 4; ++b) acc[a][b] = zf;
#pragma unroll
    for (int c = 0; c < 4; ++c)
#pragma unroll
      for (int rt = 0; rt < 2; ++rt)
#pragma unroll
        for (int ct = 0; ct < 4; ++ct)
          acc[rt][ct] = __builtin_amdgcn_mfma_f32_16x16x32_f16(A[rt][c], B[ct][c], acc[rt][ct], 0, 0, 0);

    // epilogue for this half: sliced column stats + transpose via LDS + coalesced store
#pragma unroll
    for (int ct = 0; ct < 4; ++ct) {
      int lc = wc * 64 + ct * 16 + m;
      int gc = h * 128 + lc;
      float s = 0.f, s2 = 0.f;
#pragma unroll
      for (int rt = 0; rt < 2; ++rt) {
        int lr = wr * 32 + rt * 16 + q * 4;
#pragma unroll
        for (int i = 0; i < 4; ++i) {
          float v = acc[rt][ct][i];
          s += v; s2 += v * v;
          sh[lr + i][lc] = (f16)v;
        }
      }
      s  += __shfl_xor(s, 16);  s  += __shfl_xor(s, 32);
      s2 += __shfl_xor(s2, 16); s2 += __shfl_xor(s2, 32);
      if (q == 0) {
        unsafeAtomicAdd(&sum1s[slice * 256 + gc], s);
        unsafeAtomicAdd(&sq1s[slice * 256 + gc], s2);
      }
    }
    __syncthreads();
#pragma unroll
    for (int j = 0; j < 4; ++j) {
      int r = j * 16 + r0;
      f16x8 v = *(const f16x8*)(&sh[r][colc * 8]);
      *(f16x8*)(t1f + (long)(rbase + r) * 256 + h * 128 + colc * 8) = v;
    }
    __syncthreads(); // epilogue readback done before next half overwrites sh
  }
}

// ---------------- GEMM2: t2 = relu(BN1(t1)) @ W2, 64x128 tiles, grid 1564.
// scale1/shift1 computed per-block from sum1s/sq1s; BN1+ReLU fused into staging. Pad-row stats masked.
__global__ __launch_bounds__(256) void gemm2_kernel(const f16* __restrict__ a1,  // raw t1
                                                    const f16* __restrict__ w2f, // +l*32768, frag order
                                                    const float* __restrict__ sum1s,
                                                    const float* __restrict__ sq1s,
                                                    const float* __restrict__ g1,  // +l*256
                                                    const float* __restrict__ bt1, // +l*256
                                                    f16* __restrict__ t2out,       // hf buffer
                                                    float* __restrict__ sum2s,
                                                    float* __restrict__ sq2s) {
  __shared__ __align__(16) char ldsraw[34816]; // 32KB A-stage + 2KB sc1/sh1; epilogue reuses 0..17408
  float* sc1 = (float*)(ldsraw + 32768); // 256 f32
  float* sh1 = (float*)(ldsraw + 33792); // 256 f32
  const int tid = threadIdx.x;
  const int lane = tid & 63, w = tid >> 6;
  const int wr = w >> 1, wc = w & 1;
  const int m = lane & 15, q = lane >> 4;
  const int rbase = blockIdx.x * 64;
  const int slice = blockIdx.x & 15;

  // ---- issue staging global loads first (latency overlaps the stats phase)
  f16x8 st[8];
  const int tofs = tid * 16;
#pragma unroll
  for (int j = 0; j < 8; ++j)
    st[j] = *(const f16x8*)(a1 + (long)rbase * 256 + (tofs + j * 4096) / 2);

  // ---- per-block BN1 stats: thread t -> column t
  {
    float s = 0.f, s2 = 0.f;
#pragma unroll
    for (int k = 0; k < 16; ++k) { s += sum1s[k * 256 + tid]; s2 += sq1s[k * 256 + tid]; }
    float mu = s * (1.f / NN);
    float var = fmaxf(s2 * (1.f / NN) - mu * mu, 0.f);
    float is = rsqrtf(var + 1e-5f);
    float sc = g1[tid] * is;
    sc1[tid] = sc;
    sh1[tid] = bt1[tid] - mu * sc;
  }
  __syncthreads();

  // ---- stage A tile (64 x 256 f16 = 32KB) with fused BN+ReLU
  {
    const int k0 = (tid & 31) * 8; // same k-range for all 8 chunks of this thread
    float4 sa = *(const float4*)(sc1 + k0);
    float4 sb = *(const float4*)(sc1 + k0 + 4);
    float4 ha = *(const float4*)(sh1 + k0);
    float4 hb = *(const float4*)(sh1 + k0 + 4);
#pragma unroll
    for (int j = 0; j < 8; ++j) {
      int ofs = tofs + j * 4096;
      int row = ofs >> 9, colb = ofs & 511;
      f16x8 u = st[j], o;
      o[0] = (f16)fmaxf((float)u[0] * sa.x + ha.x, 0.f);
      o[1] = (f16)fmaxf((float)u[1] * sa.y + ha.y, 0.f);
      o[2] = (f16)fmaxf((float)u[2] * sa.z + ha.z, 0.f);
      o[3] = (f16)fmaxf((float)u[3] * sa.w + ha.w, 0.f);
      o[4] = (f16)fmaxf((float)u[4] * sb.x + hb.x, 0.f);
      o[5] = (f16)fmaxf((float)u[5] * sb.y + hb.y, 0.f);
      o[6] = (f16)fmaxf((float)u[6] * sb.z + hb.z, 0.f);
      o[7] = (f16)fmaxf((float)u[7] * sb.w + hb.w, 0.f);
      *(f16x8*)(ldsraw + row * 512 + (colb ^ ((row & 7) << 4))) = o;
    }
  }
  __syncthreads();

  f32x4 acc[2][4];
  const f32x4 zf = {0.f, 0.f, 0.f, 0.f};
#pragma unroll
  for (int a = 0; a < 2; ++a)
#pragma unroll
    for (int b = 0; b < 4; ++b) acc[a][b] = zf;

#pragma unroll
  for (int hh = 0; hh < 2; ++hh) { // K=256 in two halves
    f16x8 A[2][4], B[4][4];
#pragma unroll
    for (int rt = 0; rt < 2; ++rt) {
      int row = wr * 32 + rt * 16 + m;
      int rs = row * 512, sw = (row & 7) << 4;
#pragma unroll
      for (int c = 0; c < 4; ++c) {
        int colb = (hh * 4 + c) * 64 + q * 16;
        A[rt][c] = *(const f16x8*)(ldsraw + rs + (colb ^ sw));
      }
    }
#pragma unroll
    for (int ct = 0; ct < 4; ++ct)
#pragma unroll
      for (int c = 0; c < 4; ++c)
        B[ct][c] = *(const f16x8*)(w2f + (((wc * 4 + ct) * 8 + hh * 4 + c) * 64 + lane) * 8);
#pragma unroll
    for (int c = 0; c < 4; ++c)
#pragma unroll
      for (int rt = 0; rt < 2; ++rt)
#pragma unroll
        for (int ct = 0; ct < 4; ++ct)
          acc[rt][ct] = __builtin_amdgcn_mfma_f32_16x16x32_f16(A[rt][c], B[ct][c], acc[rt][ct], 0, 0, 0);
  }

  __syncthreads(); // A-stage region dead; reuse for epilogue transpose
  f16 (*sh)[136] = (f16(*)[136])ldsraw;

  // epilogue: masked stats (pad rows >= NN excluded) + LDS transpose + coalesced store
#pragma unroll
  for (int ct = 0; ct < 4; ++ct) {
    int gc = wc * 64 + ct * 16 + m;
    float s = 0.f, s2 = 0.f;
#pragma unroll
    for (int rt = 0; rt < 2; ++rt) {
      int grow = rbase + wr * 32 + rt * 16 + q * 4;
      int lr = wr * 32 + rt * 16 + q * 4;
#pragma unroll
      for (int i = 0; i < 4; ++i) {
        float v = acc[rt][ct][i];
        float vv = (grow + i < NN) ? v : 0.f;
        s += vv; s2 += vv * vv;
        sh[lr + i][gc] = (f16)v;
      }
    }
    s  += __shfl_xor(s, 16);  s  += __shfl_xor(s, 32);
    s2 += __shfl_xor(s2, 16); s2 += __shfl_xor(s2, 32);
    if (q == 0) {
      unsafeAtomicAdd(&sum2s[slice * 128 + gc], s);
      unsafeAtomicAdd(&sq2s[slice * 128 + gc], s2);
    }
  }
  __syncthreads();
  const int colc = tid & 15, r0 = tid >> 4;
#pragma unroll
  for (int j = 0; j < 4; ++j) {
    int r = j * 16 + r0;
    f16x8 v = *(const f16x8*)(&sh[r][colc * 8]);
    *(f16x8*)(t2out + (long)(rbase + r) * 128 + colc * 8) = v;
  }
}

// ---------------- apply (l==4 only): out = BN2(t2) f32, per-block stats2, grid 1564 x 64 rows
__global__ __launch_bounds__(256) void apply_kernel(const f16* __restrict__ t2,
                                                    const float* __restrict__ sum2s,
                                                    const float* __restrict__ sq2s,
                                                    const float* __restrict__ g2,  // g_out+512
                                                    const float* __restrict__ bt2, // bt_out+512
                                                    float* __restrict__ outp) {
  __shared__ float sc2[128], sh2[128];
  const int tid = threadIdx.x;
  if (tid < 128) {
    float s = 0.f, s2 = 0.f;
#pragma unroll
    for (int k = 0; k < 16; ++k) { s += sum2s[k * 128 + tid]; s2 += sq2s[k * 128 + tid]; }
    float mu = s * (1.f / NN);
    float var = fmaxf(s2 * (1.f / NN) - mu * mu, 0.f);
    float is = rsqrtf(var + 1e-5f);
    float sc = g2[tid] * is;
    sc2[tid] = sc;
    sh2[tid] = bt2[tid] - mu * sc;
  }
  __syncthreads();
  const int rbase = blockIdx.x * 64;
#pragma unroll
  for (int k = 0; k < 4; ++k) {
    int ci = tid + k * 256;
    int r = ci >> 4, c8 = ci & 15;
    int row = rbase + r;
    if (row >= NN) continue;
    f16x8 u = *(const f16x8*)(t2 + (long)row * 128 + c8 * 8);
    float4 sa = *(const float4*)(sc2 + c8 * 8);
    float4 sb = *(const float4*)(sc2 + c8 * 8 + 4);
    float4 ha = *(const float4*)(sh2 + c8 * 8);
    float4 hb = *(const float4*)(sh2 + c8 * 8 + 4);
    float4 o0 = {(float)u[0] * sa.x + ha.x, (float)u[1] * sa.y + ha.y,
                 (float)u[2] * sa.z + ha.z, (float)u[3] * sa.w + ha.w};
    float4 o1 = {(float)u[4] * sb.x + hb.x, (float)u[5] * sb.y + hb.y,
                 (float)u[6] * sb.z + hb.z, (float)u[7] * sb.w + hb.w};
    *(float4*)(outp + (long)row * 128 + c8 * 8) = o0;
    *(float4*)(outp + (long)row * 128 + c8 * 8 + 4) = o1;
  }
}

extern "C" void kernel_launch(void* const* d_in, const int* in_sizes, int n_in,
                              void* d_out, int out_size, void* d_ws, size_t ws_size,
                              hipStream_t stream) {
  (void)in_sizes; (void)n_in; (void)out_size; (void)ws_size;
  const int*   x      = (const int*)d_in[0];
  const int*   ei     = (const int*)d_in[1];
  const int*   ea     = (const int*)d_in[2];
  const float* ew     = (const float*)d_in[3];
  const float* aemb   = (const float*)d_in[4];
  const float* bemb   = (const float*)d_in[5];
  const float* eps    = (const float*)d_in[6];
  const float* W1     = (const float*)d_in[7];
  const float* g1     = (const float*)d_in[9];
  const float* bt1    = (const float*)d_in[10];
  const float* W2     = (const float*)d_in[11];
  const float* g_out  = (const float*)d_in[13];
  const float* bt_out = (const float*)d_in[14];

  float* outp = (float*)d_out;

  // ws layout (extent unchanged: ends 108,403,360):
  //   [0, 25,624,576):             hf   (NP x 128 f16) — atom h (layer 0) / t2
  //   [25,624,576, 51,249,152):    zb   (NP x 128 f16) — z
  //   [51,249,152, 102,498,304):   t1f  (NP x 256 f16) — raw t1
  //   w1f, w2f (frag order), slices, offs, bsum, deg, cursor, pkw (int2, replaces pk+wsrt).
  //   bsumtab (655,360 B) overlays deg+cursor (dead after scatter).
  char* ws = (char*)d_ws;
  f16*   hf    = (f16*)(ws);
  f16*   zb    = (f16*)(ws + 25624576);
  f16*   t1f   = (f16*)(ws + 51249152);
  f16*   w1f   = (f16*)(ws + 102498304);  // 327,680 B
  f16*   w2f   = (f16*)(ws + 102825984);  // 327,680 B -> 103,153,664
  float* slices= (float*)(ws + 103153664); // 49,152 B -> 103,202,816
  int*   offs  = (int*)(ws + 103202816);   // 400,032 B -> 103,602,848
  int*   bsum  = (int*)(ws + 103602848);   // 512 B -> 103,603,360
  int*   deg   = (int*)(ws + 103603360);   // 400,000 B -> 104,003,360
  int*   cursor= (int*)(ws + 104003360);   // 400,000 B -> 104,403,360
  f16*   bsumtab = (f16*)(ws + 103603360); // 655,360 B overlay on deg+cursor
  int2*  pkw   = (int2*)(ws + 104403360);  // 4,000,000 B -> ends 108,403,360

  float* sum1s = slices;        // 16*256
  float* sq1s  = slices + 4096; // 16*256
  float* sum2s = slices + 8192; // 16*128
  float* sq2s  = slices + 10240;// 16*128

  init_kernel<<<1719, 256, 0, stream>>>(W1, W2, w1f, w2f, deg, slices);
  hist_kernel<<<1954, 256, 0, stream>>>(ei, deg);
  scan1_kernel<<<98, 256, 0, stream>>>(deg, offs, bsum);
  scan2_kernel<<<1, 64, 0, stream>>>(bsum, 98);
  scan3_kernel<<<392, 256, 0, stream>>>(offs, bsum, cursor);
  scatter_kernel<<<1954, 256, 0, stream>>>(ei, ea, ew, cursor, pkw);
  bondtab_kernel<<<1280, 256, 0, stream>>>(bemb, bsumtab); // after scatter: deg/cursor dead
  atom_kernel<<<12500, 256, 0, stream>>>(x, aemb, hf);

  for (int l = 0; l < 5; ++l) {
    if (l == 0) {
      edge_agg_kernel<<<6256, 256, 0, stream>>>(offs, pkw, bsumtab, eps, hf, zb);
    } else {
      edge_agg_bn_kernel<<<6256, 256, 0, stream>>>(offs, pkw, bsumtab + l * 65536, eps, l,
                                                   hf, sum2s, sq2s,
                                                   g_out + (l - 1) * 128, bt_out + (l - 1) * 128,
                                                   sum1s, zb);
    }
    gemm1_kernel<<<1564, 256, 0, stream>>>(zb, w1f + l * 32768, t1f, sum1s, sq1s, sum2s);
    gemm2_kernel<<<1564, 256, 0, stream>>>(t1f, w2f + l * 32768, sum1s, sq1s,
                                           g1 + l * 256, bt1 + l * 256, hf, sum2s, sq2s);
    if (l == 4)
      apply_kernel<<<1564, 256, 0, stream>>>(hf, sum2s, sq2s, g_out + 512, bt_out + 512, outp);
  }
}

// Round 12
// 585.645 us; speedup vs baseline: 1.0195x; 1.0195x over previous
//
#include <hip/hip_runtime.h>
#include <hip/hip_bf16.h>
#include <hip/hip_fp16.h>

#define NN 100000
#define EE 500000
#define NP 100096  // NN padded to 1564*64

typedef _Float16 f16;
typedef __attribute__((ext_vector_type(8))) _Float16 f16x8;
typedef __attribute__((ext_vector_type(4))) _Float16 f16x4;
typedef __attribute__((ext_vector_type(4))) float f32x4;

static __device__ __forceinline__ f16x8 relu8(f16x8 a) {
#if __has_builtin(__builtin_elementwise_max)
  f16x8 z = {0, 0, 0, 0, 0, 0, 0, 0};
  return __builtin_elementwise_max(a, z);
#else
  f16x8 r;
#pragma unroll
  for (int i = 0; i < 8; ++i) r[i] = (a[i] > (f16)0) ? a[i] : (f16)0;
  return r;
#endif
}

// ---------------- init: W1/W2 -> MFMA-fragment order, zero deg, zero stat slices, zero dmeta
__global__ __launch_bounds__(256) void init_kernel(const float* __restrict__ W1,
                                                   const float* __restrict__ W2,
                                                   f16* __restrict__ w1f,
                                                   f16* __restrict__ w2f,
                                                   int* __restrict__ deg,
                                                   float* __restrict__ slices,
                                                   int* __restrict__ dmeta) { // dhist(64)+dcur(64)
  int gid = blockIdx.x * 256 + threadIdx.x;
  if (gid < 163840) {
    int l = gid / 32768; int rem = gid % 32768;
    int k = rem / 256;   int n = rem % 256;
    int ctg = n >> 4, m = n & 15;
    int c = k >> 5, q = (k >> 3) & 3, e = k & 7;
    int lane = q * 16 + m;
    w1f[l * 32768 + ((ctg * 4 + c) * 64 + lane) * 8 + e] = (f16)W1[gid];
  } else if (gid < 327680) {
    int g = gid - 163840;
    int l = g / 32768; int rem = g % 32768;
    int k = rem / 128; int n = rem % 128;
    int ctg = n >> 4, m = n & 15;
    int c = k >> 5, q = (k >> 3) & 3, e = k & 7;
    int lane = q * 16 + m;
    w2f[l * 32768 + ((ctg * 8 + c) * 64 + lane) * 8 + e] = (f16)W2[g];
  } else if (gid < 427680) {
    int i = gid - 327680;
    if (i < NN) deg[i] = 0;
  } else if (gid < 439968) {
    slices[gid - 427680] = 0.f;
  } else if (gid < 440096) {
    dmeta[gid - 439968] = 0;
  }
}

// ---------------- bond-sum table: tab[l][combo][d] = sum_f bemb[l][f][a_f][d], combo=a0|a1<<3|a2<<6
__global__ __launch_bounds__(256) void bondtab_kernel(const float* __restrict__ bemb,
                                                      f16* __restrict__ tab) {
  int gid = blockIdx.x * 256 + threadIdx.x; // 1280 blocks = 327,680 = 5*512*128
  int l = gid >> 16;
  int rem = gid & 65535;
  int combo = rem >> 7, d = rem & 127;
  int a0 = combo & 7, a1 = (combo >> 3) & 7, a2 = combo >> 6;
  const float* bl = bemb + l * 3072;
  float v = bl[a0 * 128 + d] + bl[1024 + a1 * 128 + d] + bl[2048 + a2 * 128 + d];
  tab[gid] = (f16)v;
}

// ---------------- CSR build ----------------
__global__ __launch_bounds__(256) void hist_kernel(const int* __restrict__ ei, int* __restrict__ deg) {
  int e = blockIdx.x * 256 + threadIdx.x;
  if (e < EE) atomicAdd(&deg[ei[EE + e]], 1);
}

__global__ __launch_bounds__(256) void scan1_kernel(const int* __restrict__ deg,
                                                    int* __restrict__ offs,
                                                    int* __restrict__ bsum) {
  __shared__ int sh[256];
  int b = blockIdx.x, t = threadIdx.x;
  int base = b * 1024 + t * 4;
  int v[4];
  int s = 0;
#pragma unroll
  for (int i = 0; i < 4; ++i) { v[i] = (base + i < NN) ? deg[base + i] : 0; s += v[i]; }
  sh[t] = s;
  __syncthreads();
  for (int off = 1; off < 256; off <<= 1) {
    int x = (t >= off) ? sh[t - off] : 0;
    __syncthreads();
    sh[t] += x;
    __syncthreads();
  }
  int excl = sh[t] - s;
  if (t == 255) bsum[b] = sh[255];
  int run = excl;
#pragma unroll
  for (int i = 0; i < 4; ++i) {
    if (base + i < NN) offs[base + i] = run;
    run += v[i];
  }
}

__global__ void scan2_kernel(int* __restrict__ bsum, int nb) {
  if (threadIdx.x == 0 && blockIdx.x == 0) {
    int run = 0;
    for (int i = 0; i < nb; ++i) { int v = bsum[i]; bsum[i] = run; run += v; }
  }
}

__global__ __launch_bounds__(256) void scan3_kernel(int* __restrict__ offs,
                                                    const int* __restrict__ bsum,
                                                    int* __restrict__ cursor) {
  int i = blockIdx.x * 256 + threadIdx.x;
  if (i < NN) {
    int v = offs[i] + bsum[i >> 10];
    offs[i] = v;
    cursor[i] = v;
  } else if (i == NN) {
    offs[NN] = EE;
  }
}

// pkw.x = src(17b) | a0<<17 | a1<<20 | a2<<23 ; pkw.y = bits of edge weight
__global__ __launch_bounds__(256) void scatter_kernel(const int* __restrict__ ei,
                                                      const int* __restrict__ ea,
                                                      const float* __restrict__ ew,
                                                      int* __restrict__ cursor,
                                                      int2* __restrict__ pkw) {
  int e = blockIdx.x * 256 + threadIdx.x;
  if (e >= EE) return;
  int dst = ei[EE + e];
  int pos = atomicAdd(&cursor[dst], 1);
  int src = ei[e];
  int a0 = ea[e * 3 + 0], a1 = ea[e * 3 + 1], a2 = ea[e * 3 + 2];
  pkw[pos] = make_int2(src | (a0 << 17) | (a1 << 20) | (a2 << 23), __float_as_int(ew[e]));
}

// ---------------- degree-balanced permutation: counting sort of nodes by min(deg,63)
__global__ __launch_bounds__(256) void dhist_kernel(const int* __restrict__ deg,
                                                    int* __restrict__ dhist) {
  __shared__ int lh[64];
  int t = threadIdx.x;
  if (t < 64) lh[t] = 0;
  __syncthreads();
  int n = blockIdx.x * 256 + t;
  if (n < NN) {
    int d = deg[n]; if (d > 63) d = 63;
    atomicAdd(&lh[d], 1);
  }
  __syncthreads();
  if (t < 64 && lh[t] > 0) atomicAdd(&dhist[t], lh[t]);
}

__global__ void dscan_kernel(const int* __restrict__ dhist, int* __restrict__ dcur) {
  if (threadIdx.x == 0 && blockIdx.x == 0) {
    int run = 0;
    for (int i = 0; i < 64; ++i) { int v = dhist[i]; dcur[i] = run; run += v; }
  }
}

__global__ __launch_bounds__(256) void dscatter_kernel(const int* __restrict__ deg,
                                                       int* __restrict__ dcur,
                                                       int* __restrict__ norder) {
  __shared__ int lcnt[64], lbase[64];
  int t = threadIdx.x;
  if (t < 64) lcnt[t] = 0;
  __syncthreads();
  int n = blockIdx.x * 256 + t;
  int b = 0, lpos = 0;
  bool valid = (n < NN);
  if (valid) {
    b = deg[n]; if (b > 63) b = 63;
    lpos = atomicAdd(&lcnt[b], 1);
  }
  __syncthreads();
  if (t < 64 && lcnt[t] > 0) lbase[t] = atomicAdd(&dcur[t], lcnt[t]);
  __syncthreads();
  if (valid) norder[lbase[b] + lpos] = n;
}

// ---------------- atom embedding: hf16[n,d] = (f16) sum_f atom_emb[f, x[n,f], d] ----------------
__global__ __launch_bounds__(256) void atom_kernel(const int* __restrict__ x,
                                                   const float* __restrict__ aemb,
                                                   f16* __restrict__ hf) {
  int gid = blockIdx.x * 256 + threadIdx.x;
  int n = gid >> 5, qq = gid & 31;
  if (n >= NN) return;
  float4 s = {0.f, 0.f, 0.f, 0.f};
#pragma unroll
  for (int f = 0; f < 9; ++f) {
    int xi = x[n * 9 + f];
    float4 v = *(const float4*)(aemb + (f * 120 + xi) * 128 + qq * 4);
    s.x += v.x; s.y += v.y; s.z += v.z; s.w += v.w;
  }
  f16x4 o;
  o[0] = (f16)s.x; o[1] = (f16)s.y; o[2] = (f16)s.z; o[3] = (f16)s.w;
  *(f16x4*)(hf + (long)n * 128 + qq * 4) = o;
}

// ---------------- edge aggregate, layer 0: z = (1+eps)*h + sum relu(h[src]+bsum)*w
// degree-balanced node order (waves see equal-degree nodes); 2-deep pipeline; packed pkw.
__global__ __launch_bounds__(256) void edge_agg_kernel(const int* __restrict__ offs,
                                                       const int2* __restrict__ pkw,
                                                       const f16* __restrict__ tab, // l=0 slice
                                                       const float* __restrict__ eps,
                                                       const int* __restrict__ norder,
                                                       const f16* __restrict__ hf,
                                                       f16* __restrict__ zb) {
  int gid = blockIdx.x * 256 + threadIdx.x; // NP*16 threads exactly
  int g = gid >> 4, d0 = (gid & 15) * 8;
  if (g >= NN) {
    f16x8 z = {0, 0, 0, 0, 0, 0, 0, 0};
    *(f16x8*)(zb + (long)g * 128 + d0) = z;
    return;
  }
  int n = norder[g];
  int s0 = offs[n], s1 = offs[n + 1];
  float e1 = 1.f + eps[0];
  f16x8 hn = *(const f16x8*)(hf + (long)n * 128 + d0);
  float acc[8];
#pragma unroll
  for (int i = 0; i < 8; ++i) acc[i] = e1 * (float)hn[i];

  float wA, wB; f16x8 hA, bA, hB, bB;
  if (s0 < s1) {
    int2 pw = pkw[s0]; wA = __int_as_float(pw.y);
    hA = *(const f16x8*)(hf + (long)(pw.x & 131071) * 128 + d0);
    bA = *(const f16x8*)(tab + ((pw.x >> 17) & 511) * 128 + d0);
  }
  if (s0 + 1 < s1) {
    int2 pw = pkw[s0 + 1]; wB = __int_as_float(pw.y);
    hB = *(const f16x8*)(hf + (long)(pw.x & 131071) * 128 + d0);
    bB = *(const f16x8*)(tab + ((pw.x >> 17) & 511) * 128 + d0);
  }
  int e = s0;
  for (; e + 1 < s1; e += 2) {
    {
      f16x8 sm = relu8(hA + bA);
#pragma unroll
      for (int i = 0; i < 8; ++i) acc[i] += (float)sm[i] * wA;
      if (e + 2 < s1) {
        int2 pw = pkw[e + 2]; wA = __int_as_float(pw.y);
        hA = *(const f16x8*)(hf + (long)(pw.x & 131071) * 128 + d0);
        bA = *(const f16x8*)(tab + ((pw.x >> 17) & 511) * 128 + d0);
      }
    }
    {
      f16x8 sm = relu8(hB + bB);
#pragma unroll
      for (int i = 0; i < 8; ++i) acc[i] += (float)sm[i] * wB;
      if (e + 3 < s1) {
        int2 pw = pkw[e + 3]; wB = __int_as_float(pw.y);
        hB = *(const f16x8*)(hf + (long)(pw.x & 131071) * 128 + d0);
        bB = *(const f16x8*)(tab + ((pw.x >> 17) & 511) * 128 + d0);
      }
    }
  }
  if (e < s1) {
    f16x8 sm = relu8(hA + bA);
#pragma unroll
    for (int i = 0; i < 8; ++i) acc[i] += (float)sm[i] * wA;
  }
  f16x8 o;
#pragma unroll
  for (int i = 0; i < 8; ++i) o[i] = (f16)acc[i];
  *(f16x8*)(zb + (long)n * 128 + d0) = o;
}

// ---------------- edge aggregate, layers 1..4: h = relu(BN2(t2)) on the fly (packed f16),
// degree-balanced order, 2-deep pipeline; block 0 re-zeroes sum1s/sq1s for this layer's gemm1.
__global__ __launch_bounds__(256) void edge_agg_bn_kernel(const int* __restrict__ offs,
                                                          const int2* __restrict__ pkw,
                                                          const f16* __restrict__ tab, // + l*65536
                                                          const float* __restrict__ eps, int l,
                                                          const int* __restrict__ norder,
                                                          const f16* __restrict__ t2,  // prev t2 (hf buf)
                                                          const float* __restrict__ sum2s,
                                                          const float* __restrict__ sq2s,
                                                          const float* __restrict__ g2,  // g_out+(l-1)*128
                                                          const float* __restrict__ bt2, // bt_out+(l-1)*128
                                                          float* __restrict__ s1z,       // sum1s base (8192 f32)
                                                          f16* __restrict__ zb) {
  __shared__ float sc2[128], sh2[128];
  const int tid = threadIdx.x;
  if (tid < 128) {
    float s = 0.f, s2 = 0.f;
#pragma unroll
    for (int k = 0; k < 16; ++k) { s += sum2s[k * 128 + tid]; s2 += sq2s[k * 128 + tid]; }
    float mu = s * (1.f / NN);
    float var = fmaxf(s2 * (1.f / NN) - mu * mu, 0.f);
    float is = rsqrtf(var + 1e-5f);
    float sc = g2[tid] * is;
    sc2[tid] = sc;
    sh2[tid] = bt2[tid] - mu * sc;
  }
  if (blockIdx.x == 0) { // re-zero sum1s+sq1s for this layer's gemm1
#pragma unroll
    for (int j = 0; j < 8; ++j)
      *(float4*)(s1z + (j * 256 + tid) * 4) = float4{0.f, 0.f, 0.f, 0.f};
  }
  __syncthreads();
  int gid = blockIdx.x * 256 + tid;
  int g = gid >> 4, d0 = (gid & 15) * 8;
  if (g >= NN) {
    f16x8 z = {0, 0, 0, 0, 0, 0, 0, 0};
    *(f16x8*)(zb + (long)g * 128 + d0) = z;
    return;
  }
  int n = norder[g];
  float4 svA = *(const float4*)(sc2 + d0), svB = *(const float4*)(sc2 + d0 + 4);
  float4 shA = *(const float4*)(sh2 + d0), shB = *(const float4*)(sh2 + d0 + 4);
  float sv[8] = {svA.x, svA.y, svA.z, svA.w, svB.x, svB.y, svB.z, svB.w};
  float hv[8] = {shA.x, shA.y, shA.z, shA.w, shB.x, shB.y, shB.z, shB.w};
  f16x8 sv8, hv8;
#pragma unroll
  for (int i = 0; i < 8; ++i) { sv8[i] = (f16)sv[i]; hv8[i] = (f16)hv[i]; }

  int s0 = offs[n], s1 = offs[n + 1];
  float e1 = 1.f + eps[l];
  f16x8 hn = *(const f16x8*)(t2 + (long)n * 128 + d0);
  float acc[8];
#pragma unroll
  for (int i = 0; i < 8; ++i)
    acc[i] = e1 * fmaxf((float)hn[i] * sv[i] + hv[i], 0.f);

  float wA, wB; f16x8 hA, bA, hB, bB;
  if (s0 < s1) {
    int2 pw = pkw[s0]; wA = __int_as_float(pw.y);
    hA = *(const f16x8*)(t2 + (long)(pw.x & 131071) * 128 + d0);
    bA = *(const f16x8*)(tab + ((pw.x >> 17) & 511) * 128 + d0);
  }
  if (s0 + 1 < s1) {
    int2 pw = pkw[s0 + 1]; wB = __int_as_float(pw.y);
    hB = *(const f16x8*)(t2 + (long)(pw.x & 131071) * 128 + d0);
    bB = *(const f16x8*)(tab + ((pw.x >> 17) & 511) * 128 + d0);
  }
  int e = s0;
  for (; e + 1 < s1; e += 2) {
    {
      f16x8 y = relu8(hA * sv8 + hv8);
      f16x8 sm = relu8(y + bA);
#pragma unroll
      for (int i = 0; i < 8; ++i) acc[i] += (float)sm[i] * wA;
      if (e + 2 < s1) {
        int2 pw = pkw[e + 2]; wA = __int_as_float(pw.y);
        hA = *(const f16x8*)(t2 + (long)(pw.x & 131071) * 128 + d0);
        bA = *(const f16x8*)(tab + ((pw.x >> 17) & 511) * 128 + d0);
      }
    }
    {
      f16x8 y = relu8(hB * sv8 + hv8);
      f16x8 sm = relu8(y + bB);
#pragma unroll
      for (int i = 0; i < 8; ++i) acc[i] += (float)sm[i] * wB;
      if (e + 3 < s1) {
        int2 pw = pkw[e + 3]; wB = __int_as_float(pw.y);
        hB = *(const f16x8*)(t2 + (long)(pw.x & 131071) * 128 + d0);
        bB = *(const f16x8*)(tab + ((pw.x >> 17) & 511) * 128 + d0);
      }
    }
  }
  if (e < s1) {
    f16x8 y = relu8(hA * sv8 + hv8);
    f16x8 sm = relu8(y + bA);
#pragma unroll
    for (int i = 0; i < 8; ++i) acc[i] += (float)sm[i] * wA;
  }
  f16x8 o;
#pragma unroll
  for (int i = 0; i < 8; ++i) o[i] = (f16)acc[i];
  *(f16x8*)(zb + (long)n * 128 + d0) = o;
}

// ---------------- GEMM1: t1 = z @ W1, 64x128 tiles, grid (2,1564) [round-9 form].
// Block (0,0) re-zeroes sum2s/sq2s for this layer's gemm2 atomics.
__global__ __launch_bounds__(256) void gemm1_kernel(const f16* __restrict__ zb,
                                                    const f16* __restrict__ w1f, // +l*32768, frag order
                                                    f16* __restrict__ t1f,
                                                    float* __restrict__ sum1s,
                                                    float* __restrict__ sq1s,
                                                    float* __restrict__ s2z) { // sum2s base (4096 f32)
  __shared__ __align__(16) char ldsraw[17408]; // A-stage 16KB; epilogue [64][136] f16
  const int tid = threadIdx.x;
  const int lane = tid & 63, w = tid >> 6;
  const int wr = w >> 1, wc = w & 1;
  const int m = lane & 15, q = lane >> 4;
  const int cb = blockIdx.x;
  const int rbase = blockIdx.y * 64;
  const int slice = blockIdx.y & 15;

  if (blockIdx.y == 0 && cb == 0) { // re-zero sum2s+sq2s
#pragma unroll
    for (int j = 0; j < 4; ++j)
      *(float4*)(s2z + (j * 256 + tid) * 4) = float4{0.f, 0.f, 0.f, 0.f};
  }

  // ---- B fragments: lane-contiguous 1KB loads, L1/L2-hot
  f16x8 B[4][4];
#pragma unroll
  for (int ct = 0; ct < 4; ++ct)
#pragma unroll
    for (int c = 0; c < 4; ++c)
      B[ct][c] = *(const f16x8*)(w1f + (((cb * 8 + wc * 4 + ct) * 4 + c) * 64 + lane) * 8);

  // ---- stage A tile (64 x 128 f16 = 16KB): 4 x 16B per thread, contiguous global
  {
    f16x8 st[4];
    const int tofs = tid * 16;
#pragma unroll
    for (int j = 0; j < 4; ++j)
      st[j] = *(const f16x8*)(zb + (long)rbase * 128 + (tofs + j * 4096) / 2);
#pragma unroll
    for (int j = 0; j < 4; ++j) {
      int ofs = tofs + j * 4096;
      int row = ofs >> 8, colb = ofs & 255;
      *(f16x8*)(ldsraw + row * 256 + (colb ^ ((row & 7) << 4))) = st[j];
    }
  }
  __syncthreads();

  // ---- A fragments from LDS (swizzled, conflict-free)
  f16x8 A[2][4];
#pragma unroll
  for (int rt = 0; rt < 2; ++rt) {
    int row = wr * 32 + rt * 16 + m;
    int rs = row * 256, sw = (row & 7) << 4;
#pragma unroll
    for (int c = 0; c < 4; ++c) {
      int colb = c * 64 + q * 16;
      A[rt][c] = *(const f16x8*)(ldsraw + rs + (colb ^ sw));
    }
  }

  f32x4 acc[2][4];
  const f32x4 zf = {0.f, 0.f, 0.f, 0.f};
#pragma unroll
  for (int a = 0; a < 2; ++a)
#pragma unroll
    for (int b = 0; b < 4; ++b) acc[a][b] = zf;

#pragma unroll
  for (int c = 0; c < 4; ++c)
#pragma unroll
    for (int rt = 0; rt < 2; ++rt)
#pragma unroll
      for (int ct = 0; ct < 4; ++ct)
        acc[rt][ct] = __builtin_amdgcn_mfma_f32_16x16x32_f16(A[rt][c], B[ct][c], acc[rt][ct], 0, 0, 0);

  __syncthreads(); // A-stage region dead; reuse as epilogue transpose buffer
  f16 (*sh)[136] = (f16(*)[136])ldsraw;

  // epilogue: sliced column stats + f16 tile to LDS (transpose)
#pragma unroll
  for (int ct = 0; ct < 4; ++ct) {
    int lc = wc * 64 + ct * 16 + m;
    int gc = cb * 128 + lc;
    float s = 0.f, s2 = 0.f;
#pragma unroll
    for (int rt = 0; rt < 2; ++rt) {
      int lr = wr * 32 + rt * 16 + q * 4;
#pragma unroll
      for (int i = 0; i < 4; ++i) {
        float v = acc[rt][ct][i];
        s += v; s2 += v * v;
        sh[lr + i][lc] = (f16)v;
      }
    }
    s  += __shfl_xor(s, 16);  s  += __shfl_xor(s, 32);
    s2 += __shfl_xor(s2, 16); s2 += __shfl_xor(s2, 32);
    if (q == 0) {
      unsafeAtomicAdd(&sum1s[slice * 256 + gc], s);
      unsafeAtomicAdd(&sq1s[slice * 256 + gc], s2);
    }
  }
  __syncthreads();
  // coalesced readback: thread -> (row r, 8-col chunk)
  const int colc = tid & 15, r0 = tid >> 4;
#pragma unroll
  for (int j = 0; j < 4; ++j) {
    int r = j * 16 + r0;
    f16x8 v = *(const f16x8*)(&sh[r][colc * 8]);
    *(f16x8*)(t1f + (long)(rbase + r) * 256 + cb * 128 + colc * 8) = v;
  }
}

// ---------------- GEMM2: t2 = relu(BN1(t1)) @ W2, 64x128 tiles, grid 1564.
// scale1/shift1 computed per-block from sum1s/sq1s; BN1+ReLU fused into staging. Pad-row stats masked.
__global__ __launch_bounds__(256) void gemm2_kernel(const f16* __restrict__ a1,  // raw t1
                                                    const f16* __restrict__ w2f, // +l*32768, frag order
                                                    const float* __restrict__ sum1s,
                                                    const float* __restrict__ sq1s,
                                                    const float* __restrict__ g1,  // +l*256
                                                    const float* __restrict__ bt1, // +l*256
                                                    f16* __restrict__ t2out,       // hf buffer
                                                    float* __restrict__ sum2s,
                                                    float* __restrict__ sq2s) {
  __shared__ __align__(16) char ldsraw[34816]; // 32KB A-stage + 2KB sc1/sh1; epilogue reuses 0..17408
  float* sc1 = (float*)(ldsraw + 32768); // 256 f32
  float* sh1 = (float*)(ldsraw + 33792); // 256 f32
  const int tid = threadIdx.x;
  const int lane = tid & 63, w = tid >> 6;
  const int wr = w >> 1, wc = w & 1;
  const int m = lane & 15, q = lane >> 4;
  const int rbase = blockIdx.x * 64;
  const int slice = blockIdx.x & 15;

  // ---- issue staging global loads first (latency overlaps the stats phase)
  f16x8 st[8];
  const int tofs = tid * 16;
#pragma unroll
  for (int j = 0; j < 8; ++j)
    st[j] = *(const f16x8*)(a1 + (long)rbase * 256 + (tofs + j * 4096) / 2);

  // ---- per-block BN1 stats: thread t -> column t
  {
    float s = 0.f, s2 = 0.f;
#pragma unroll
    for (int k = 0; k < 16; ++k) { s += sum1s[k * 256 + tid]; s2 += sq1s[k * 256 + tid]; }
    float mu = s * (1.f / NN);
    float var = fmaxf(s2 * (1.f / NN) - mu * mu, 0.f);
    float is = rsqrtf(var + 1e-5f);
    float sc = g1[tid] * is;
    sc1[tid] = sc;
    sh1[tid] = bt1[tid] - mu * sc;
  }
  __syncthreads();

  // ---- stage A tile (64 x 256 f16 = 32KB) with fused BN+ReLU
  {
    const int k0 = (tid & 31) * 8; // same k-range for all 8 chunks of this thread
    float4 sa = *(const float4*)(sc1 + k0);
    float4 sb = *(const float4*)(sc1 + k0 + 4);
    float4 ha = *(const float4*)(sh1 + k0);
    float4 hb = *(const float4*)(sh1 + k0 + 4);
#pragma unroll
    for (int j = 0; j < 8; ++j) {
      int ofs = tofs + j * 4096;
      int row = ofs >> 9, colb = ofs & 511;
      f16x8 u = st[j], o;
      o[0] = (f16)fmaxf((float)u[0] * sa.x + ha.x, 0.f);
      o[1] = (f16)fmaxf((float)u[1] * sa.y + ha.y, 0.f);
      o[2] = (f16)fmaxf((float)u[2] * sa.z + ha.z, 0.f);
      o[3] = (f16)fmaxf((float)u[3] * sa.w + ha.w, 0.f);
      o[4] = (f16)fmaxf((float)u[4] * sb.x + hb.x, 0.f);
      o[5] = (f16)fmaxf((float)u[5] * sb.y + hb.y, 0.f);
      o[6] = (f16)fmaxf((float)u[6] * sb.z + hb.z, 0.f);
      o[7] = (f16)fmaxf((float)u[7] * sb.w + hb.w, 0.f);
      *(f16x8*)(ldsraw + row * 512 + (colb ^ ((row & 7) << 4))) = o;
    }
  }
  __syncthreads();

  f32x4 acc[2][4];
  const f32x4 zf = {0.f, 0.f, 0.f, 0.f};
#pragma unroll
  for (int a = 0; a < 2; ++a)
#pragma unroll
    for (int b = 0; b < 4; ++b) acc[a][b] = zf;

#pragma unroll
  for (int hh = 0; hh < 2; ++hh) { // K=256 in two halves
    f16x8 A[2][4], B[4][4];
#pragma unroll
    for (int rt = 0; rt < 2; ++rt) {
      int row = wr * 32 + rt * 16 + m;
      int rs = row * 512, sw = (row & 7) << 4;
#pragma unroll
      for (int c = 0; c < 4; ++c) {
        int colb = (hh * 4 + c) * 64 + q * 16;
        A[rt][c] = *(const f16x8*)(ldsraw + rs + (colb ^ sw));
      }
    }
#pragma unroll
    for (int ct = 0; ct < 4; ++ct)
#pragma unroll
      for (int c = 0; c < 4; ++c)
        B[ct][c] = *(const f16x8*)(w2f + (((wc * 4 + ct) * 8 + hh * 4 + c) * 64 + lane) * 8);
#pragma unroll
    for (int c = 0; c < 4; ++c)
#pragma unroll
      for (int rt = 0; rt < 2; ++rt)
#pragma unroll
        for (int ct = 0; ct < 4; ++ct)
          acc[rt][ct] = __builtin_amdgcn_mfma_f32_16x16x32_f16(A[rt][c], B[ct][c], acc[rt][ct], 0, 0, 0);
  }

  __syncthreads(); // A-stage region dead; reuse for epilogue transpose
  f16 (*sh)[136] = (f16(*)[136])ldsraw;

  // epilogue: masked stats (pad rows >= NN excluded) + LDS transpose + coalesced store
#pragma unroll
  for (int ct = 0; ct < 4; ++ct) {
    int gc = wc * 64 + ct * 16 + m;
    float s = 0.f, s2 = 0.f;
#pragma unroll
    for (int rt = 0; rt < 2; ++rt) {
      int grow = rbase + wr * 32 + rt * 16 + q * 4;
      int lr = wr * 32 + rt * 16 + q * 4;
#pragma unroll
      for (int i = 0; i < 4; ++i) {
        float v = acc[rt][ct][i];
        float vv = (grow + i < NN) ? v : 0.f;
        s += vv; s2 += vv * vv;
        sh[lr + i][gc] = (f16)v;
      }
    }
    s  += __shfl_xor(s, 16);  s  += __shfl_xor(s, 32);
    s2 += __shfl_xor(s2, 16); s2 += __shfl_xor(s2, 32);
    if (q == 0) {
      unsafeAtomicAdd(&sum2s[slice * 128 + gc], s);
      unsafeAtomicAdd(&sq2s[slice * 128 + gc], s2);
    }
  }
  __syncthreads();
  const int colc = tid & 15, r0 = tid >> 4;
#pragma unroll
  for (int j = 0; j < 4; ++j) {
    int r = j * 16 + r0;
    f16x8 v = *(const f16x8*)(&sh[r][colc * 8]);
    *(f16x8*)(t2out + (long)(rbase + r) * 128 + colc * 8) = v;
  }
}

// ---------------- apply (l==4 only): out = BN2(t2) f32, per-block stats2, grid 1564 x 64 rows
__global__ __launch_bounds__(256) void apply_kernel(const f16* __restrict__ t2,
                                                    const float* __restrict__ sum2s,
                                                    const float* __restrict__ sq2s,
                                                    const float* __restrict__ g2,  // g_out+512
                                                    const float* __restrict__ bt2, // bt_out+512
                                                    float* __restrict__ outp) {
  __shared__ float sc2[128], sh2[128];
  const int tid = threadIdx.x;
  if (tid < 128) {
    float s = 0.f, s2 = 0.f;
#pragma unroll
    for (int k = 0; k < 16; ++k) { s += sum2s[k * 128 + tid]; s2 += sq2s[k * 128 + tid]; }
    float mu = s * (1.f / NN);
    float var = fmaxf(s2 * (1.f / NN) - mu * mu, 0.f);
    float is = rsqrtf(var + 1e-5f);
    float sc = g2[tid] * is;
    sc2[tid] = sc;
    sh2[tid] = bt2[tid] - mu * sc;
  }
  __syncthreads();
  const int rbase = blockIdx.x * 64;
#pragma unroll
  for (int k = 0; k < 4; ++k) {
    int ci = tid + k * 256;
    int r = ci >> 4, c8 = ci & 15;
    int row = rbase + r;
    if (row >= NN) continue;
    f16x8 u = *(const f16x8*)(t2 + (long)row * 128 + c8 * 8);
    float4 sa = *(const float4*)(sc2 + c8 * 8);
    float4 sb = *(const float4*)(sc2 + c8 * 8 + 4);
    float4 ha = *(const float4*)(sh2 + c8 * 8);
    float4 hb = *(const float4*)(sh2 + c8 * 8 + 4);
    float4 o0 = {(float)u[0] * sa.x + ha.x, (float)u[1] * sa.y + ha.y,
                 (float)u[2] * sa.z + ha.z, (float)u[3] * sa.w + ha.w};
    float4 o1 = {(float)u[4] * sb.x + hb.x, (float)u[5] * sb.y + hb.y,
                 (float)u[6] * sb.z + hb.z, (float)u[7] * sb.w + hb.w};
    *(float4*)(outp + (long)row * 128 + c8 * 8) = o0;
    *(float4*)(outp + (long)row * 128 + c8 * 8 + 4) = o1;
  }
}

extern "C" void kernel_launch(void* const* d_in, const int* in_sizes, int n_in,
                              void* d_out, int out_size, void* d_ws, size_t ws_size,
                              hipStream_t stream) {
  (void)in_sizes; (void)n_in; (void)out_size; (void)ws_size;
  const int*   x      = (const int*)d_in[0];
  const int*   ei     = (const int*)d_in[1];
  const int*   ea     = (const int*)d_in[2];
  const float* ew     = (const float*)d_in[3];
  const float* aemb   = (const float*)d_in[4];
  const float* bemb   = (const float*)d_in[5];
  const float* eps    = (const float*)d_in[6];
  const float* W1     = (const float*)d_in[7];
  const float* g1     = (const float*)d_in[9];
  const float* bt1    = (const float*)d_in[10];
  const float* W2     = (const float*)d_in[11];
  const float* g_out  = (const float*)d_in[13];
  const float* bt_out = (const float*)d_in[14];

  float* outp = (float*)d_out;

  // ws layout (ends 108,804,256 < 109.0 MB known-good extent):
  //   [0, 25,624,576):             hf   (NP x 128 f16) — atom h (layer 0) / t2
  //   [25,624,576, 51,249,152):    zb   (NP x 128 f16) — z
  //   [51,249,152, 102,498,304):   t1f  (NP x 256 f16) — raw t1
  //   w1f, w2f (frag order), slices, offs, bsum, deg, cursor, pkw (int2),
  //   norder (degree-sorted node permutation) + dmeta at the tail.
  //   bsumtab (655,360 B) overlays deg+cursor (dead after dscatter).
  char* ws = (char*)d_ws;
  f16*   hf    = (f16*)(ws);
  f16*   zb    = (f16*)(ws + 25624576);
  f16*   t1f   = (f16*)(ws + 51249152);
  f16*   w1f   = (f16*)(ws + 102498304);  // 327,680 B
  f16*   w2f   = (f16*)(ws + 102825984);  // 327,680 B -> 103,153,664
  float* slices= (float*)(ws + 103153664); // 49,152 B -> 103,202,816
  int*   offs  = (int*)(ws + 103202816);   // 400,032 B -> 103,602,848
  int*   bsum  = (int*)(ws + 103602848);   // 512 B -> 103,603,360
  int*   deg   = (int*)(ws + 103603360);   // 400,000 B -> 104,003,360
  int*   cursor= (int*)(ws + 104003360);   // 400,000 B -> 104,403,360
  f16*   bsumtab = (f16*)(ws + 103603360); // 655,360 B overlay on deg+cursor
  int2*  pkw   = (int2*)(ws + 104403360);  // 4,000,000 B -> 108,403,360
  int*   norder= (int*)(ws + 108403360);   // 400,384 B -> 108,803,744
  int*   dmeta = (int*)(ws + 108803744);   // dhist(64)+dcur(64) = 512 B -> 108,804,256

  int* dhist = dmeta;
  int* dcur  = dmeta + 64;

  float* sum1s = slices;        // 16*256
  float* sq1s  = slices + 4096; // 16*256
  float* sum2s = slices + 8192; // 16*128
  float* sq2s  = slices + 10240;// 16*128

  init_kernel<<<1720, 256, 0, stream>>>(W1, W2, w1f, w2f, deg, slices, dmeta);
  hist_kernel<<<1954, 256, 0, stream>>>(ei, deg);
  scan1_kernel<<<98, 256, 0, stream>>>(deg, offs, bsum);
  scan2_kernel<<<1, 64, 0, stream>>>(bsum, 98);
  scan3_kernel<<<392, 256, 0, stream>>>(offs, bsum, cursor);
  scatter_kernel<<<1954, 256, 0, stream>>>(ei, ea, ew, cursor, pkw);
  dhist_kernel<<<391, 256, 0, stream>>>(deg, dhist);
  dscan_kernel<<<1, 64, 0, stream>>>(dhist, dcur);
  dscatter_kernel<<<391, 256, 0, stream>>>(deg, dcur, norder);
  bondtab_kernel<<<1280, 256, 0, stream>>>(bemb, bsumtab); // after dscatter: deg/cursor dead
  atom_kernel<<<12500, 256, 0, stream>>>(x, aemb, hf);

  for (int l = 0; l < 5; ++l) {
    if (l == 0) {
      edge_agg_kernel<<<6256, 256, 0, stream>>>(offs, pkw, bsumtab, eps, norder, hf, zb);
    } else {
      edge_agg_bn_kernel<<<6256, 256, 0, stream>>>(offs, pkw, bsumtab + l * 65536, eps, l,
                                                   norder, hf, sum2s, sq2s,
                                                   g_out + (l - 1) * 128, bt_out + (l - 1) * 128,
                                                   sum1s, zb);
    }
    gemm1_kernel<<<dim3(2, 1564), 256, 0, stream>>>(zb, w1f + l * 32768, t1f, sum1s, sq1s, sum2s);
    gemm2_kernel<<<1564, 256, 0, stream>>>(t1f, w2f + l * 32768, sum1s, sq1s,
                                           g1 + l * 256, bt1 + l * 256, hf, sum2s, sq2s);
    if (l == 4)
      apply_kernel<<<1564, 256, 0, stream>>>(hf, sum2s, sq2s, g_out + 512, bt_out + 512, outp);
  }
}